// Round 3
// baseline (126.738 us; speedup 1.0000x reference)
//
#include <hip/hip_runtime.h>
#include <math.h>

#define MAXGT 128
#define POS_LIMIT 128
#define TOTAL 256

// -------- device helpers --------

__device__ __forceinline__ void stage_gt(const float* __restrict__ gt, int M,
                                         float4* sbox, float* sarea) {
#pragma clang fp contract(off)
    int tid = threadIdx.x;
    if (tid < M) {
        float4 b = ((const float4*)gt)[tid];
        sbox[tid] = b;
        sarea[tid] = (b.z - b.x) * (b.w - b.y);
    }
    __syncthreads();
}

// argmax_j IoU(a, gt_j) — replicates numpy fp32 op order exactly (no fma
// contraction, IEEE divide, strict > keeps first occurrence of max).
__device__ __forceinline__ int iou_argmax(float4 a, int M,
                                          const float4* sbox, const float* sarea) {
#pragma clang fp contract(off)
    float areaA = (a.z - a.x) * (a.w - a.y);
    float best = -INFINITY;
    int bi = 0;
    for (int j = 0; j < M; ++j) {
        float4 b = sbox[j];
        float lt0 = fmaxf(a.x, b.x);
        float lt1 = fmaxf(a.y, b.y);
        float rb0 = fminf(a.z, b.z);
        float rb1 = fminf(a.w, b.w);
        float w = fmaxf(rb0 - lt0, 0.0f);
        float h = fmaxf(rb1 - lt1, 0.0f);
        float inter = w * h;
        float iou = inter / ((areaA + sarea[j]) - inter);
        if (iou > best) { best = iou; bi = j; }
    }
    return bi;
}

// loss for one selected sample (exact fp32 op order, no contraction)
__device__ __forceinline__ void sample_loss(const float* __restrict__ score,
                                            const float* __restrict__ pred,
                                            const float* __restrict__ anchors,
                                            const float* __restrict__ gt,
                                            int sel, int g, int label,
                                            float& cls, float& reg) {
#pragma clang fp contract(off)
    float s0 = score[2 * sel], s1 = score[2 * sel + 1];
    float m = fmaxf(s0, s1);
    float sh0 = s0 - m, sh1 = s1 - m;
    float lse = logf(expf(sh0) + expf(sh1));
    cls = -((label ? sh1 : sh0) - lse);

    reg = 0.0f;
    if (label) {
        float4 a = ((const float4*)anchors)[sel];
        float4 gb = ((const float4*)gt)[g];
        float aw = a.z - a.x, ah = a.w - a.y;
        float acx = a.x + 0.5f * aw, acy = a.y + 0.5f * ah;
        float gw = gb.z - gb.x, gh = gb.w - gb.y;
        float gcx = gb.x + 0.5f * gw, gcy = gb.y + 0.5f * gh;
        float4 p = ((const float4*)pred)[sel];
        float d0 = p.x - (gcx - acx) / aw;
        float d1 = p.y - (gcy - acy) / ah;
        float d2 = p.z - logf(gw / aw);
        float d3 = p.w - logf(gh / ah);
        float a0 = fabsf(d0), a1 = fabsf(d1), a2 = fabsf(d2), a3 = fabsf(d3);
        float sm0 = (a0 < 1.0f) ? 0.5f * d0 * d0 : a0 - 0.5f;
        float sm1 = (a1 < 1.0f) ? 0.5f * d1 * d1 : a1 - 0.5f;
        float sm2 = (a2 < 1.0f) ? 0.5f * d2 * d2 : a2 - 0.5f;
        float sm3 = (a3 < 1.0f) ? 0.5f * d3 * d3 : a3 - 0.5f;
        reg = 2.0f * (sm0 + sm1 + sm2 + sm3);
    }
}

// -------- kernel 1: per-anchor argmax + per-block counts; last block scans ----

__global__ void __launch_bounds__(256)
k1_count_scan(const float* __restrict__ anchors, const float* __restrict__ gt,
              int N, int M, int nb,
              unsigned char* __restrict__ g8,
              int* __restrict__ blockPos, int* __restrict__ blockNeg,
              int* __restrict__ posBase, int* __restrict__ negBase,
              int* __restrict__ curPosOut, int* __restrict__ ticket) {
    __shared__ float4 sbox[MAXGT];
    __shared__ float sarea[MAXGT];
    __shared__ int wp[4], wn[4];
    __shared__ int amLast;
    __shared__ int sp[256], sn[256];

    stage_gt(gt, M, sbox, sarea);

    int tid = threadIdx.x;
    int i = blockIdx.x * 256 + tid;
    int posf = 0, negf = 0;
    if (i < N) {
        float4 a = ((const float4*)anchors)[i];
        int bi = iou_argmax(a, M, sbox, sarea);
        g8[i] = (unsigned char)bi;
        posf = (bi >= 1);
        negf = (bi == 0);
    }
    unsigned long long pm = __ballot(posf);
    unsigned long long nm = __ballot(negf);
    int lane = tid & 63, wave = tid >> 6;
    if (lane == 0) { wp[wave] = __popcll(pm); wn[wave] = __popcll(nm); }
    __syncthreads();
    if (tid == 0) {
        blockPos[blockIdx.x] = wp[0] + wp[1] + wp[2] + wp[3];
        blockNeg[blockIdx.x] = wn[0] + wn[1] + wn[2] + wn[3];
        __threadfence();                       // release: counts visible device-wide
        amLast = (atomicAdd(ticket, 1) == nb - 1);
    }
    __syncthreads();
    if (!amLast) return;

    // ---- elected last block: exclusive scan of block counts ----
    __threadfence();                           // acquire
    const volatile int* vbp = (const volatile int*)blockPos;
    const volatile int* vbn = (const volatile int*)blockNeg;
    int chunk = (nb + 255) / 256;
    int s0 = tid * chunk;
    int lp = 0, ln = 0;
    for (int k = 0; k < chunk; ++k) {
        int idx = s0 + k;
        if (idx < nb) { lp += vbp[idx]; ln += vbn[idx]; }
    }
    sp[tid] = lp; sn[tid] = ln;
    __syncthreads();
    for (int off = 1; off < 256; off <<= 1) {
        int vp = (tid >= off) ? sp[tid - off] : 0;
        int vn = (tid >= off) ? sn[tid - off] : 0;
        __syncthreads();
        sp[tid] += vp; sn[tid] += vn;
        __syncthreads();
    }
    int basep = (tid == 0) ? 0 : sp[tid - 1];
    int basen = (tid == 0) ? 0 : sn[tid - 1];
    for (int k = 0; k < chunk; ++k) {
        int idx = s0 + k;
        if (idx < nb) {
            posBase[idx] = basep; negBase[idx] = basen;
            basep += vbp[idx]; basen += vbn[idx];
        }
    }
    if (tid == 255) *curPosOut = min(sp[255], POS_LIMIT);
}

// -------- kernel 2: scatter selected indices; last block computes losses ----

__global__ void __launch_bounds__(256)
k2_select_loss(const float* __restrict__ score, const float* __restrict__ pred,
               const float* __restrict__ anchors, const float* __restrict__ gt,
               const unsigned char* __restrict__ g8, int N, int nb,
               const int* __restrict__ posBase, const int* __restrict__ negBase,
               const int* __restrict__ curPosPtr,
               int* __restrict__ pos_sel, int* __restrict__ pos_gt,
               int* __restrict__ neg_sel, int* __restrict__ neg_gt,
               int* __restrict__ ticket, float* __restrict__ out) {
    __shared__ int wpo[4], wno[4];
    __shared__ int amLast;
    int b = blockIdx.x, tid = threadIdx.x;
    int pb = posBase[b], nbse = negBase[b];
    bool active = !(pb >= POS_LIMIT && nbse >= TOTAL);
    if (active) {
        int i = b * 256 + tid;
        int g = 0, valid = (i < N);
        if (valid) g = g8[i];
        int posf = valid && (g >= 1);
        int negf = valid && (g == 0);
        unsigned long long pm = __ballot(posf);
        unsigned long long nm = __ballot(negf);
        int lane = tid & 63, wave = tid >> 6;
        if (lane == 0) { wpo[wave] = __popcll(pm); wno[wave] = __popcll(nm); }
        __syncthreads();
        int poff = 0, noff = 0;
        for (int w = 0; w < wave; ++w) { poff += wpo[w]; noff += wno[w]; }
        unsigned long long ltmask = (1ull << lane) - 1ull;
        int prank = pb + poff + __popcll(pm & ltmask);
        int nrank = nbse + noff + __popcll(nm & ltmask);
        if (posf && prank < POS_LIMIT) { pos_sel[prank] = i; pos_gt[prank] = g; }
        if (negf && nrank < TOTAL)     { neg_sel[nrank] = i; neg_gt[nrank] = g; }
    }
    __syncthreads();
    if (tid == 0) {
        __threadfence();                       // release
        amLast = (atomicAdd(ticket, 1) == nb - 1);
    }
    __syncthreads();
    if (!amLast) return;

    // ---- elected last block: loss over the 256 selected samples ----
    __threadfence();                           // acquire
    const volatile int* vps = (const volatile int*)pos_sel;
    const volatile int* vpg = (const volatile int*)pos_gt;
    const volatile int* vns = (const volatile int*)neg_sel;
    const volatile int* vng = (const volatile int*)neg_gt;
    int curPos = *curPosPtr;
    int sel, label, g;
    if (tid < curPos) { sel = vps[tid]; g = vpg[tid]; label = 1; }
    else              { int k = tid - curPos; sel = vns[k]; g = vng[k]; label = 0; }

    float cls, reg;
    sample_loss(score, pred, anchors, gt, sel, g, label, cls, reg);

    for (int off = 32; off > 0; off >>= 1) {
        cls += __shfl_down(cls, off);
        reg += __shfl_down(reg, off);
    }
    __shared__ float rc[4], rr[4];
    int lane = tid & 63, wave = tid >> 6;
    if (lane == 0) { rc[wave] = cls; rr[wave] = reg; }
    __syncthreads();
    if (tid == 0) {
        out[0] = (rc[0] + rc[1] + rc[2] + rc[3]) * (1.0f / 256.0f);  // CLS_W = 1
        out[1] = (rr[0] + rr[1] + rr[2] + rr[3]) * (1.0f / 256.0f);  // REG_W folded
    }
}

// -------- host launch --------

extern "C" void kernel_launch(void* const* d_in, const int* in_sizes, int n_in,
                              void* d_out, int out_size, void* d_ws, size_t ws_size,
                              hipStream_t stream) {
    const float* rpn_score = (const float*)d_in[0];
    const float* rpn_pred  = (const float*)d_in[1];
    const float* anchors   = (const float*)d_in[2];
    const float* gt        = (const float*)d_in[3];
    int N = in_sizes[2] / 4;
    int M = in_sizes[3] / 4;
    if (M > MAXGT) M = MAXGT;

    int nb = (N + 255) / 256;

    // workspace layout
    int* w = (int*)d_ws;
    int* tickets  = w;            w += 2;   // [0]=K1, [1]=K2 (zeroed below)
    int* blockPos = w;            w += nb;
    int* blockNeg = w;            w += nb;
    int* posBase  = w;            w += nb;
    int* negBase  = w;            w += nb;
    int* curPos   = w;            w += 1;
    int* pos_sel  = w;            w += POS_LIMIT;
    int* pos_gt   = w;            w += POS_LIMIT;
    int* neg_sel  = w;            w += TOTAL;
    int* neg_gt   = w;            w += TOTAL;
    unsigned char* g8 = (unsigned char*)w;

    (void)hipMemsetAsync(tickets, 0, 2 * sizeof(int), stream);
    k1_count_scan<<<nb, 256, 0, stream>>>(anchors, gt, N, M, nb, g8,
                                          blockPos, blockNeg, posBase, negBase,
                                          curPos, &tickets[0]);
    k2_select_loss<<<nb, 256, 0, stream>>>(rpn_score, rpn_pred, anchors, gt, g8,
                                           N, nb, posBase, negBase, curPos,
                                           pos_sel, pos_gt, neg_sel, neg_gt,
                                           &tickets[1], (float*)d_out);
}

// Round 4
// 94.194 us; speedup vs baseline: 1.3455x; 1.3455x over previous
//
#include <hip/hip_runtime.h>
#include <math.h>

#define MAXGT 128
#define POS_LIMIT 128
#define TOTAL 256

// -------- kernel 1: per-anchor IoU argmax -> g8 (one byte per anchor) --------
// Replicates numpy fp32 op order exactly: no fma contraction, IEEE divide,
// strict > keeps first occurrence of the max (np.argmax semantics).
// No fences/atomics: cross-kernel visibility comes from the kernel boundary.

__global__ void __launch_bounds__(256)
k1_argmax(const float* __restrict__ anchors, const float* __restrict__ gt,
          int N, int M, unsigned char* __restrict__ g8) {
#pragma clang fp contract(off)
    __shared__ float4 sbox[MAXGT];
    __shared__ float sarea[MAXGT];
    int tid = threadIdx.x;
    if (tid < M) {
        float4 b = ((const float4*)gt)[tid];
        sbox[tid] = b;
        sarea[tid] = (b.z - b.x) * (b.w - b.y);
    }
    __syncthreads();

    int i = blockIdx.x * 256 + tid;
    if (i >= N) return;
    float4 a = ((const float4*)anchors)[i];
    float areaA = (a.z - a.x) * (a.w - a.y);
    float best = -INFINITY;
    int bi = 0;
#pragma unroll 5
    for (int j = 0; j < M; ++j) {
        float4 b = sbox[j];
        float lt0 = fmaxf(a.x, b.x);
        float lt1 = fmaxf(a.y, b.y);
        float rb0 = fminf(a.z, b.z);
        float rb1 = fminf(a.w, b.w);
        float w = fmaxf(rb0 - lt0, 0.0f);
        float h = fmaxf(rb1 - lt1, 0.0f);
        float inter = w * h;
        float iou = inter / ((areaA + sarea[j]) - inter);
        if (iou > best) { best = iou; bi = j; }
    }
    g8[i] = (unsigned char)bi;
}

// -------- kernel 2: single block — select first-K pos/neg in index order,
//                    then compute both losses --------

__global__ void __launch_bounds__(256)
k2_select_loss(const float* __restrict__ score, const float* __restrict__ pred,
               const float* __restrict__ anchors, const float* __restrict__ gt,
               const unsigned char* __restrict__ g8, int N,
               float* __restrict__ out) {
#pragma clang fp contract(off)
    __shared__ int s_ps[POS_LIMIT], s_pg[POS_LIMIT];
    __shared__ int s_ns[TOTAL], s_ng[TOTAL];
    __shared__ int wpo[4], wno[4];

    int tid = threadIdx.x;
    int lane = tid & 63, wave = tid >> 6;
    unsigned long long ltmask = (1ull << lane) - 1ull;

    // walk anchors in 256-chunks until both quotas are filled (positives are
    // ~90%, negatives ~10% of anchors -> ~11 chunks of the 1172 total)
    int posCnt = 0, negCnt = 0;
    int nchunks = (N + 255) >> 8;
    for (int c = 0; c < nchunks && (posCnt < POS_LIMIT || negCnt < TOTAL); ++c) {
        int i = (c << 8) + tid;
        int valid = (i < N);
        int g = valid ? (int)g8[i] : 0;
        int posf = valid && (g >= 1);
        int negf = valid && (g == 0);
        unsigned long long pm = __ballot(posf);
        unsigned long long nm = __ballot(negf);
        if (lane == 0) { wpo[wave] = __popcll(pm); wno[wave] = __popcll(nm); }
        __syncthreads();
        int poff = 0, noff = 0, ptot = 0, ntot = 0;
        for (int w = 0; w < 4; ++w) {
            int cp = wpo[w], cn = wno[w];
            if (w < wave) { poff += cp; noff += cn; }
            ptot += cp; ntot += cn;
        }
        int prank = posCnt + poff + __popcll(pm & ltmask);
        int nrank = negCnt + noff + __popcll(nm & ltmask);
        if (posf && prank < POS_LIMIT) { s_ps[prank] = i; s_pg[prank] = g; }
        if (negf && nrank < TOTAL)     { s_ns[nrank] = i; s_ng[nrank] = g; }
        posCnt += ptot; negCnt += ntot;
        __syncthreads();   // scatter visible + wpo/wno consumed before reuse
    }

    int curPos = min(posCnt, POS_LIMIT);
    int sel, label, g;
    if (tid < curPos) {
        sel = s_ps[tid]; g = s_pg[tid]; label = 1;
    } else {
        int k = tid - curPos;
        if (k >= negCnt) k = (negCnt > 0) ? negCnt - 1 : 0;  // safety clamp
        sel = s_ns[k]; g = s_ng[k]; label = 0;
    }

    // classification: -log_softmax(score[sel])[label]
    float s0 = score[2 * sel], s1 = score[2 * sel + 1];
    float m = fmaxf(s0, s1);
    float sh0 = s0 - m, sh1 = s1 - m;
    float lse = logf(expf(sh0) + expf(sh1));
    float cls = -((label ? sh1 : sh0) - lse);

    // regression: smooth-L1 on encoded targets, inside weight = label
    float reg = 0.0f;
    if (label) {
        float4 a = ((const float4*)anchors)[sel];
        float4 gb = ((const float4*)gt)[g];
        float aw = a.z - a.x, ah = a.w - a.y;
        float acx = a.x + 0.5f * aw, acy = a.y + 0.5f * ah;
        float gw = gb.z - gb.x, gh = gb.w - gb.y;
        float gcx = gb.x + 0.5f * gw, gcy = gb.y + 0.5f * gh;
        float4 p = ((const float4*)pred)[sel];
        float d0 = p.x - (gcx - acx) / aw;
        float d1 = p.y - (gcy - acy) / ah;
        float d2 = p.z - logf(gw / aw);
        float d3 = p.w - logf(gh / ah);
        float a0 = fabsf(d0), a1 = fabsf(d1), a2 = fabsf(d2), a3 = fabsf(d3);
        float sm0 = (a0 < 1.0f) ? 0.5f * d0 * d0 : a0 - 0.5f;
        float sm1 = (a1 < 1.0f) ? 0.5f * d1 * d1 : a1 - 0.5f;
        float sm2 = (a2 < 1.0f) ? 0.5f * d2 * d2 : a2 - 0.5f;
        float sm3 = (a3 < 1.0f) ? 0.5f * d3 * d3 : a3 - 0.5f;
        reg = 2.0f * (sm0 + sm1 + sm2 + sm3);
    }

    // block reduce (wave shuffle + LDS across 4 waves)
    for (int off = 32; off > 0; off >>= 1) {
        cls += __shfl_down(cls, off);
        reg += __shfl_down(reg, off);
    }
    __shared__ float rc[4], rr[4];
    if (lane == 0) { rc[wave] = cls; rr[wave] = reg; }
    __syncthreads();
    if (tid == 0) {
        out[0] = (rc[0] + rc[1] + rc[2] + rc[3]) * (1.0f / 256.0f);  // CLS_W = 1
        out[1] = (rr[0] + rr[1] + rr[2] + rr[3]) * (1.0f / 256.0f);  // REG_W folded
    }
}

// -------- host launch --------

extern "C" void kernel_launch(void* const* d_in, const int* in_sizes, int n_in,
                              void* d_out, int out_size, void* d_ws, size_t ws_size,
                              hipStream_t stream) {
    const float* rpn_score = (const float*)d_in[0];
    const float* rpn_pred  = (const float*)d_in[1];
    const float* anchors   = (const float*)d_in[2];
    const float* gt        = (const float*)d_in[3];
    int N = in_sizes[2] / 4;
    int M = in_sizes[3] / 4;
    if (M > MAXGT) M = MAXGT;

    int nb = (N + 255) / 256;
    unsigned char* g8 = (unsigned char*)d_ws;   // N bytes

    k1_argmax<<<nb, 256, 0, stream>>>(anchors, gt, N, M, g8);
    k2_select_loss<<<1, 256, 0, stream>>>(rpn_score, rpn_pred, anchors, gt,
                                          g8, N, (float*)d_out);
}

// Round 6
// 75.894 us; speedup vs baseline: 1.6699x; 1.2411x over previous
//
#include <hip/hip_runtime.h>
#include <math.h>

#define MAXGT 128
#define POS_LIMIT 128
#define TOTAL 256
#define PREFIX 65536   // k1 computes g8 for min(N, PREFIX); k2 falls back to
                       // inline argmax past it (never taken for this input)

// argmax_j IoU(a, gt_j) — replicates numpy fp32 op order exactly (no fma
// contraction, IEEE divide, strict > keeps first occurrence of the max).
__device__ __forceinline__ int iou_argmax(float4 a, int M,
                                          const float4* sbox, const float* sarea) {
#pragma clang fp contract(off)
    float areaA = (a.z - a.x) * (a.w - a.y);
    float best = -INFINITY;
    int bi = 0;
#pragma unroll 5
    for (int j = 0; j < M; ++j) {
        float4 b = sbox[j];
        float lt0 = fmaxf(a.x, b.x);
        float lt1 = fmaxf(a.y, b.y);
        float rb0 = fminf(a.z, b.z);
        float rb1 = fminf(a.w, b.w);
        float w = fmaxf(rb0 - lt0, 0.0f);
        float h = fmaxf(rb1 - lt1, 0.0f);
        float inter = w * h;
        float iou = inter / ((areaA + sarea[j]) - inter);
        if (iou > best) { best = iou; bi = j; }
    }
    return bi;
}

__device__ __forceinline__ void stage_gt(const float* __restrict__ gt, int M,
                                         float4* sbox, float* sarea) {
#pragma clang fp contract(off)
    int tid = threadIdx.x;
    if (tid < M) {
        float4 b = ((const float4*)gt)[tid];
        sbox[tid] = b;
        sarea[tid] = (b.z - b.x) * (b.w - b.y);
    }
    __syncthreads();
}

// -------- kernel 1: IoU argmax for the first min(N,PREFIX) anchors --------

__global__ void __launch_bounds__(256)
k1_argmax(const float* __restrict__ anchors, const float* __restrict__ gt,
          int N, int M, unsigned char* __restrict__ g8) {
    __shared__ float4 sbox[MAXGT];
    __shared__ float sarea[MAXGT];
    stage_gt(gt, M, sbox, sarea);
    int i = blockIdx.x * 256 + threadIdx.x;
    if (i >= N) return;
    float4 a = ((const float4*)anchors)[i];
    g8[i] = (unsigned char)iou_argmax(a, M, sbox, sarea);
}

// -------- kernel 2: single block — select first-K pos/neg in index order,
//                    then compute both losses --------

__global__ void __launch_bounds__(256)
k2_select_loss(const float* __restrict__ score, const float* __restrict__ pred,
               const float* __restrict__ anchors, const float* __restrict__ gt,
               const unsigned char* __restrict__ g8, int N, int M, int P,
               float* __restrict__ out) {
#pragma clang fp contract(off)
    __shared__ float4 sbox[MAXGT];
    __shared__ float sarea[MAXGT];
    __shared__ int s_ps[POS_LIMIT], s_pg[POS_LIMIT];
    __shared__ int s_ns[TOTAL], s_ng[TOTAL];
    __shared__ int wpo[4], wno[4];

    stage_gt(gt, M, sbox, sarea);

    int tid = threadIdx.x;
    int lane = tid & 63, wave = tid >> 6;
    unsigned long long ltmask = (1ull << lane) - 1ull;

    // walk anchors in 256-chunks; quota: 128 positives and 256-curPos
    // negatives. Once posCnt>=128, curPos saturates at 128 -> need 128 negs.
    int posCnt = 0, negCnt = 0;
    int nchunks = (N + 255) >> 8;
    for (int c = 0; c < nchunks; ++c) {
        if (posCnt >= POS_LIMIT && negCnt >= (TOTAL - POS_LIMIT)) break;
        int i = (c << 8) + tid;
        int valid = (i < N);
        int g = 0;
        if (valid) {
            if (i < P) g = (int)g8[i];
            else {  // fallback: prefix exhausted (not taken for bench input)
                float4 a = ((const float4*)anchors)[i];
                g = iou_argmax(a, M, sbox, sarea);
            }
        }
        int posf = valid && (g >= 1);
        int negf = valid && (g == 0);
        unsigned long long pm = __ballot(posf);
        unsigned long long nm = __ballot(negf);
        if (lane == 0) { wpo[wave] = __popcll(pm); wno[wave] = __popcll(nm); }
        __syncthreads();
        int poff = 0, noff = 0, ptot = 0, ntot = 0;
        for (int w = 0; w < 4; ++w) {
            int cp = wpo[w], cn = wno[w];
            if (w < wave) { poff += cp; noff += cn; }
            ptot += cp; ntot += cn;
        }
        int prank = posCnt + poff + __popcll(pm & ltmask);
        int nrank = negCnt + noff + __popcll(nm & ltmask);
        if (posf && prank < POS_LIMIT) { s_ps[prank] = i; s_pg[prank] = g; }
        if (negf && nrank < TOTAL)     { s_ns[nrank] = i; s_ng[nrank] = g; }
        posCnt += ptot; negCnt += ntot;
        __syncthreads();   // scatter visible + wpo/wno consumed before reuse
    }

    int curPos = min(posCnt, POS_LIMIT);
    int sel, label, g;
    if (tid < curPos) {
        sel = s_ps[tid]; g = s_pg[tid]; label = 1;
    } else {
        int k = tid - curPos;
        if (k >= negCnt) k = (negCnt > 0) ? negCnt - 1 : 0;  // safety clamp
        sel = s_ns[k]; g = s_ng[k]; label = 0;
    }

    // classification: -log_softmax(score[sel])[label]
    float s0 = score[2 * sel], s1 = score[2 * sel + 1];
    float m = fmaxf(s0, s1);
    float sh0 = s0 - m, sh1 = s1 - m;
    float lse = logf(expf(sh0) + expf(sh1));
    float cls = -((label ? sh1 : sh0) - lse);

    // regression: smooth-L1 on encoded targets, inside weight = label
    float reg = 0.0f;
    if (label) {
        float4 a = ((const float4*)anchors)[sel];
        float4 gb = sbox[g];
        float aw = a.z - a.x, ah = a.w - a.y;
        float acx = a.x + 0.5f * aw, acy = a.y + 0.5f * ah;
        float gw = gb.z - gb.x, gh = gb.w - gb.y;
        float gcx = gb.x + 0.5f * gw, gcy = gb.y + 0.5f * gh;
        float4 p = ((const float4*)pred)[sel];
        float d0 = p.x - (gcx - acx) / aw;
        float d1 = p.y - (gcy - acy) / ah;
        float d2 = p.z - logf(gw / aw);
        float d3 = p.w - logf(gh / ah);
        float a0 = fabsf(d0), a1 = fabsf(d1), a2 = fabsf(d2), a3 = fabsf(d3);
        float sm0 = (a0 < 1.0f) ? 0.5f * d0 * d0 : a0 - 0.5f;
        float sm1 = (a1 < 1.0f) ? 0.5f * d1 * d1 : a1 - 0.5f;
        float sm2 = (a2 < 1.0f) ? 0.5f * d2 * d2 : a2 - 0.5f;
        float sm3 = (a3 < 1.0f) ? 0.5f * d3 * d3 : a3 - 0.5f;
        reg = 2.0f * (sm0 + sm1 + sm2 + sm3);
    }

    // block reduce (wave shuffle + LDS across 4 waves)
    for (int off = 32; off > 0; off >>= 1) {
        cls += __shfl_down(cls, off);
        reg += __shfl_down(reg, off);
    }
    __shared__ float rc[4], rr[4];
    if (lane == 0) { rc[wave] = cls; rr[wave] = reg; }
    __syncthreads();
    if (tid == 0) {
        out[0] = (rc[0] + rc[1] + rc[2] + rc[3]) * (1.0f / 256.0f);  // CLS_W = 1
        out[1] = (rr[0] + rr[1] + rr[2] + rr[3]) * (1.0f / 256.0f);  // REG_W folded
    }
}

// -------- host launch --------

extern "C" void kernel_launch(void* const* d_in, const int* in_sizes, int n_in,
                              void* d_out, int out_size, void* d_ws, size_t ws_size,
                              hipStream_t stream) {
    const float* rpn_score = (const float*)d_in[0];
    const float* rpn_pred  = (const float*)d_in[1];
    const float* anchors   = (const float*)d_in[2];
    const float* gt        = (const float*)d_in[3];
    int N = in_sizes[2] / 4;
    int M = in_sizes[3] / 4;
    if (M > MAXGT) M = MAXGT;

    int P = (N < PREFIX) ? N : PREFIX;
    int nb = (P + 255) / 256;                   // 256 blocks -> 1 block/CU
    unsigned char* g8 = (unsigned char*)d_ws;   // P bytes

    k1_argmax<<<nb, 256, 0, stream>>>(anchors, gt, P, M, g8);
    k2_select_loss<<<1, 256, 0, stream>>>(rpn_score, rpn_pred, anchors, gt,
                                          g8, N, M, P, (float*)d_out);
}